// Round 10
// baseline (131.111 us; speedup 1.0000x reference)
//
#include <hip/hip_runtime.h>

// SSM DPLR kernel: K[h,l] = 2*Re(C_h . dA_h^l . dB_h), dA = diag(g) + q r^T.
// R9: two-dispatch split for phase attribution + output parallelism.
//  K1 (grid 256, 256 thr): setup, G-table, partials, Toeplitz solves, T, X,
//     M (divided-difference), C-chain -> writes X + C_i rows to d_ws.
//  K2 (grid 1024, 256 thr): K[64i+j] = 2Re(sum_n C_i[n] X_j[n]), 4 blocks/head.
//  Fallback: if ws_size < 12.6 MB, launch the R8 single kernel.

#define LL 2048

struct C2 { float re, im; };

__device__ __forceinline__ C2 cmul(C2 a, C2 b){ return {a.re*b.re - a.im*b.im, a.re*b.im + a.im*b.re}; }
__device__ __forceinline__ C2 cadd(C2 a, C2 b){ return {a.re+b.re, a.im+b.im}; }
__device__ __forceinline__ C2 csub(C2 a, C2 b){ return {a.re-b.re, a.im-b.im}; }
__device__ __forceinline__ C2 cinv(C2 a){ float s=1.0f/(a.re*a.re+a.im*a.im); return {a.re*s, -a.im*s}; }
__device__ __forceinline__ C2 cscale(float s, C2 a){ return {s*a.re, s*a.im}; }
__device__ __forceinline__ C2 ld2(float2 v){ return {v.x, v.y}; }
__device__ __forceinline__ float2 st2(C2 v){ return make_float2(v.re, v.im); }

template<int CTRL>
__device__ __forceinline__ float dpp_add(float x){
  int t = __builtin_amdgcn_update_dpp(0, __float_as_int(x), CTRL, 0xF, 0xF, true);
  return x + __int_as_float(t);
}
__device__ __forceinline__ float wave_sum63(float x){
  x = dpp_add<0xB1>(x); x = dpp_add<0x4E>(x); x = dpp_add<0x124>(x);
  x = dpp_add<0x128>(x); x = dpp_add<0x142>(x); x = dpp_add<0x143>(x);
  return x;
}
__device__ __forceinline__ float bcast63(float x){
  return __int_as_float(__builtin_amdgcn_readlane(__float_as_int(x), 63));
}
__device__ __forceinline__ float rdl(float v, int l){
  return __int_as_float(__builtin_amdgcn_readlane(__float_as_int(v), l));
}
__device__ __forceinline__ C2 rdl2(C2 v, int l){ return { rdl(v.re, l), rdl(v.im, l) }; }
__device__ __forceinline__ float shr1(float x){
  return __int_as_float(__builtin_amdgcn_update_dpp(0, __float_as_int(x), 0x138, 0xF, 0xF, true));
}

// ================= shared setup macro-free helper =================
struct Setup {
    C2 g, q, r, x0, rq, rx, g16, g32, g64, Cv;
};
__device__ __forceinline__ Setup do_setup(
    const float* A_real, const float* A_imag, const float* B_real, const float* B_imag,
    const float* P_real, const float* P_imag, const float* C_real, const float* C_imag,
    const float* log_dt, int h, int lane)
{
    const int idx = h * 64 + lane;
    const float dt = expf(log_dt[h]);
    const float c  = 0.5f * dt;

    const C2 lam = { -A_real[idx], -A_imag[idx] };
    const C2 p   = {  P_real[idx],  P_imag[idx] };
    const C2 Bv  = {  B_real[idx],  B_imag[idx] };
    const C2 Cv  = {  C_real[idx],  C_imag[idx] };
    const C2 pc  = { p.re, -p.im };

    const C2 d = cinv(C2{ 1.0f - c*lam.re, -c*lam.im });
    const C2 g = cmul(d, C2{ 1.0f + c*lam.re, c*lam.im });

    C2 sv = cscale(p.re*p.re + p.im*p.im, d);
    C2 uv = cmul(cmul(d, pc), Bv);
    sv.re = bcast63(wave_sum63(sv.re)); sv.im = bcast63(wave_sum63(sv.im));
    uv.re = bcast63(wave_sum63(uv.re)); uv.im = bcast63(wave_sum63(uv.im));

    const C2 beta  = cscale(c, cinv(C2{ 1.0f + c*sv.re, c*sv.im }));
    const C2 bs    = cmul(beta, sv);
    const C2 gamma = { -c*(1.0f - bs.re), c*bs.im };

    Setup s;
    s.g  = g;
    s.q  = cmul(d, p);
    s.r  = cmul(pc, csub(gamma, cmul(beta, g)));
    s.x0 = cscale(dt, csub(cmul(d, Bv), cmul(cmul(beta, uv), s.q)));
    s.rq = cmul(s.r, s.q);
    s.rx = cmul(s.r, s.x0);
    const C2 g2 = cmul(g, g), g4 = cmul(g2, g2), g8 = cmul(g4, g4);
    s.g16 = cmul(g8, g8);
    s.g32 = cmul(s.g16, s.g16);
    s.g64 = cmul(s.g32, s.g32);
    s.Cv  = Cv;
    return s;
}

// ================= K1: per-head pipeline through the C chain =================
__global__ __launch_bounds__(256) void ssm_k1(
    const float* __restrict__ A_real, const float* __restrict__ A_imag,
    const float* __restrict__ B_real, const float* __restrict__ B_imag,
    const float* __restrict__ P_real, const float* __restrict__ P_imag,
    const float* __restrict__ C_real, const float* __restrict__ C_imag,
    const float* __restrict__ log_dt, float2* __restrict__ ws)
{
    const int h    = blockIdx.x;
    const int t    = threadIdx.x;
    const int lane = t & 63;
    const int widu = __builtin_amdgcn_readfirstlane(t >> 6);   // 0..3

    extern __shared__ char sm[];
    float2* Abuf = (float2*)sm;              // 64x64 G, then X    [32 KB]
    float2* Cs   = (float2*)(sm + 32768);    // 32x64 C_i rows     [16 KB]
    float2* prt  = (float2*)(sm + 49152);    // 512 float2         [ 4 KB]
    float2* TgA  = (float2*)(sm + 53248);    // 64
    float2* TpA  = TgA + 64;                 // 64

    const Setup S = do_setup(A_real,A_imag,B_real,B_imag,P_real,P_imag,
                             C_real,C_imag,log_dt,h,lane);
    const C2 g = S.g, q = S.q, r = S.r, x0 = S.x0, g64 = S.g64, Cv = S.Cv;

    // G-gen: rows j in [16w, 16w+16)
    {
        C2 cur = {1.0f, 0.0f};
        if (widu & 1) cur = S.g16;
        if (widu & 2) cur = cmul(cur, S.g32);
        for (int jj = 0; jj < 16; ++jj) {
            const int j = 16*widu + jj;
            Abuf[j*64 + ((lane + j) & 63)] = st2(cur);
            cur = cmul(cur, g);
        }
    }
    __syncthreads();   // B1

    // partials: w_j, a_j (lane = j), 16 n's per wave
    {
        C2 accw = {0,0}, acca = {0,0};
        for (int kk = 0; kk < 16; ++kk) {
            const int n = 16*widu + kk;
            const C2 Gv = ld2(Abuf[lane*64 + ((n + lane) & 63)]);
            accw = cadd(accw, cmul(Gv, rdl2(S.rq, n)));
            acca = cadd(acca, cmul(Gv, rdl2(S.rx, n)));
        }
        prt[widu*64 + lane]       = st2(accw);
        prt[256 + widu*64 + lane] = st2(acca);
    }
    __syncthreads();   // B2

    // solves (waves 0,1)
    C2 so = {0.0f, 0.0f};
    if (widu < 2) {
        C2 wl = {0,0};
        {
            const float2 w0 = prt[lane], w1 = prt[64+lane], w2 = prt[128+lane], w3 = prt[192+lane];
            wl.re = (w0.x+w1.x)+(w2.x+w3.x);
            wl.im = (w0.y+w1.y)+(w2.y+w3.y);
        }
        C2 va;
        if (widu == 0) {
            const float2 a0 = prt[256+lane], a1 = prt[256+64+lane], a2 = prt[256+128+lane], a3 = prt[256+192+lane];
            va.re = (a0.x+a1.x)+(a2.x+a3.x);
            va.im = (a0.y+a1.y)+(a2.y+a3.y);
        } else {
            va = wl;
        }
        C2 wsh = { shr1(wl.re), shr1(wl.im) };
        for (int j = 0; j < 64; ++j) {
            const float sr = rdl(va.re, j);
            const float si = rdl(va.im, j);
            if (lane == j) { so.re = sr; so.im = si; }
            va.re += wsh.re*sr - wsh.im*si;
            va.im += wsh.re*si + wsh.im*sr;
            wsh.re = shr1(wsh.re);
            wsh.im = shr1(wsh.im);
        }
    }
    if (widu == 0) {
        // X rebuild
        C2 x = x0;
        for (int j = 0; j < 64; ++j) {
            Abuf[j*64 + ((lane + j) & 63)] = st2(x);
            const float sjr = rdl(so.re, j);
            const float sji = rdl(so.im, j);
            const float nr = g.re*x.re - g.im*x.im + sjr*q.re - sji*q.im;
            const float ni = g.re*x.im + g.im*x.re + sjr*q.im + sji*q.re;
            x.re = nr; x.im = ni;
        }
    } else if (widu == 1) {
        // T(z) = z*P(z); T' = P + z P'
        C2 pp = rdl2(so, 0);
        C2 dd = {0,0};
        for (int i = 1; i <= 62; ++i) {
            const C2 ti = rdl2(so, i);
            const C2 nd = cadd(cmul(dd, g), pp);
            pp = cadd(cmul(pp, g), ti);
            dd = nd;
        }
        TgA[lane] = st2(cmul(g, pp));
        TpA[lane] = st2(cadd(pp, cmul(g, dd)));
    }
    __syncthreads();   // B3

    // M build: Mk[k] = M[16w+k][lane]
    C2 Mk[16];
    {
        const C2 Tgm = ld2(TgA[lane]);
        #pragma unroll
        for (int k = 0; k < 16; ++k) {
            const int n = 16*widu + k;
            const C2 gn   = rdl2(g,   n);
            const C2 qn   = rdl2(q,   n);
            const C2 g64n = rdl2(g64, n);
            const C2 Tgn  = rdl2(Tgm, n);
            const C2 idm  = cinv(csub(gn, g));
            const C2 num  = cmul(r, cadd(csub(g64n, g64), csub(Tgn, Tgm)));
            Mk[k] = cmul(cmul(qn, num), idm);
        }
        if ((lane >> 4) == widu) {
            const int k0 = lane & 15;
            const C2 Tp  = ld2(TpA[lane]);
            const C2 g63 = cmul(g64, cinv(g));
            const C2 Sd  = cmul(r, cadd(cscale(64.0f, g63), Tp));
            Mk[k0] = cadd(g64, cmul(q, Sd));
        }
    }

    // C chain
    C2 Ci = Cv;
    for (int i = 0; i < 32; ++i) {
        if (widu == 0) Cs[i*64 + lane] = st2(Ci);
        if (i == 31) break;
        C2 acc = {0,0};
        #pragma unroll
        for (int k = 0; k < 16; ++k) {
            const float cr  = rdl(Ci.re, 16*widu + k);
            const float cim = rdl(Ci.im, 16*widu + k);
            acc.re += cr*Mk[k].re - cim*Mk[k].im;
            acc.im += cr*Mk[k].im + cim*Mk[k].re;
        }
        float2* buf = prt + (i & 1)*256;
        buf[widu*64 + lane] = st2(acc);
        __syncthreads();
        const float2 p0 = buf[lane], p1 = buf[64+lane], p2 = buf[128+lane], p3 = buf[192+lane];
        Ci.re = (p0.x+p1.x)+(p2.x+p3.x);
        Ci.im = (p0.y+p1.y)+(p2.y+p3.y);
    }
    __syncthreads();   // B4

    // dump X (4096 float2) + Cs (2048 float2) to ws
    float2* wsh = ws + (size_t)h * 6144;
    #pragma unroll
    for (int s = 0; s < 16; ++s) wsh[s*256 + t] = Abuf[s*256 + t];
    #pragma unroll
    for (int s = 0; s < 8; ++s)  wsh[4096 + s*256 + t] = Cs[s*256 + t];
}

// ================= K2: output contraction, 4 blocks per head =================
__global__ __launch_bounds__(256) void ssm_k2(
    const float2* __restrict__ ws, float* __restrict__ out)
{
    const int b    = blockIdx.x;
    const int h    = b >> 2;
    const int qd   = b & 3;
    const int t    = threadIdx.x;
    const int lane = t & 63;
    const int widu = __builtin_amdgcn_readfirstlane(t >> 6);   // 0..3

    extern __shared__ char sm[];
    float2* Xs    = (float2*)sm;             // 4096 float2 [32 KB]
    float2* Crows = (float2*)(sm + 32768);   // 512 float2  [4 KB]

    const float2* wsh = ws + (size_t)h * 6144;
    #pragma unroll
    for (int s = 0; s < 16; ++s) Xs[s*256 + t] = wsh[s*256 + t];
    #pragma unroll
    for (int s = 0; s < 2; ++s) {
        const int o = s*256 + t;
        Crows[o] = wsh[4096 + qd*512 + o];
    }
    __syncthreads();

    const C2 Ca = ld2(Crows[(2*widu + 0)*64 + lane]);
    const C2 Cb = ld2(Crows[(2*widu + 1)*64 + lane]);
    float accA = 0.0f, accB = 0.0f;
    const int j = lane;
    #pragma unroll 8
    for (int n = 0; n < 64; ++n) {
        const float2 xv = Xs[j*64 + ((n + j) & 63)];
        accA += rdl(Ca.re, n)*xv.x - rdl(Ca.im, n)*xv.y;
        accB += rdl(Cb.re, n)*xv.x - rdl(Cb.im, n)*xv.y;
    }
    float* outh = out + h * LL;
    outh[(8*qd + 2*widu + 0)*64 + j] = 2.0f * accA;
    outh[(8*qd + 2*widu + 1)*64 + j] = 2.0f * accB;
}

// ================= fallback: R8 single kernel =================
__global__ __launch_bounds__(512, 2) void ssm_dplr_kernel(
    const float* __restrict__ A_real, const float* __restrict__ A_imag,
    const float* __restrict__ B_real, const float* __restrict__ B_imag,
    const float* __restrict__ P_real, const float* __restrict__ P_imag,
    const float* __restrict__ C_real, const float* __restrict__ C_imag,
    const float* __restrict__ log_dt, float* __restrict__ out)
{
    const int h    = blockIdx.x;
    const int t    = threadIdx.x;
    const int lane = t & 63;
    const int widu = __builtin_amdgcn_readfirstlane(t >> 6);

    extern __shared__ char sm[];
    float2* Abuf = (float2*)sm;
    float2* Cs   = (float2*)(sm + 32768);
    float2* prt  = (float2*)(sm + 49152);
    float2* TgA  = (float2*)(sm + 57344);
    float2* TpA  = TgA + 64;

    const Setup S = do_setup(A_real,A_imag,B_real,B_imag,P_real,P_imag,
                             C_real,C_imag,log_dt,h,lane);
    const C2 g = S.g, q = S.q, r = S.r, x0 = S.x0, g64 = S.g64, Cv = S.Cv;
    const C2 g8 = cmul(cmul(S.g16, cinv(S.g16)), S.g16); // placeholder not used

    {
        C2 cur = {1.0f, 0.0f};
        // g^(8*widu) via g16/g32 products and g^8 = sqrt(g16)? compute directly:
        C2 g8r;
        {
            const C2 g2 = cmul(g, g), g4 = cmul(g2, g2);
            g8r = cmul(g4, g4);
        }
        if (widu & 1) cur = g8r;
        if (widu & 2) cur = cmul(cur, S.g16);
        if (widu & 4) cur = cmul(cur, S.g32);
        #pragma unroll
        for (int jj = 0; jj < 8; ++jj) {
            const int j = 8*widu + jj;
            Abuf[j*64 + ((lane + j) & 63)] = st2(cur);
            cur = cmul(cur, g);
        }
    }
    __syncthreads();

    {
        C2 accw = {0,0}, acca = {0,0};
        #pragma unroll
        for (int kk = 0; kk < 8; ++kk) {
            const int n = 8*widu + kk;
            const C2 Gv = ld2(Abuf[lane*64 + ((n + lane) & 63)]);
            accw = cadd(accw, cmul(Gv, rdl2(S.rq, n)));
            acca = cadd(acca, cmul(Gv, rdl2(S.rx, n)));
        }
        prt[widu*64 + lane]       = st2(accw);
        prt[512 + widu*64 + lane] = st2(acca);
    }
    __syncthreads();

    C2 so = {0.0f, 0.0f};
    if (widu < 2) {
        C2 wl = {0,0};
        for (int w2 = 0; w2 < 8; ++w2) {
            const float2 v = prt[w2*64 + lane];
            wl.re += v.x; wl.im += v.y;
        }
        C2 va;
        if (widu == 0) {
            va = C2{0,0};
            for (int w2 = 0; w2 < 8; ++w2) {
                const float2 v = prt[512 + w2*64 + lane];
                va.re += v.x; va.im += v.y;
            }
        } else va = wl;
        C2 wsh = { shr1(wl.re), shr1(wl.im) };
        for (int j = 0; j < 64; ++j) {
            const float sr = rdl(va.re, j);
            const float si = rdl(va.im, j);
            if (lane == j) { so.re = sr; so.im = si; }
            va.re += wsh.re*sr - wsh.im*si;
            va.im += wsh.re*si + wsh.im*sr;
            wsh.re = shr1(wsh.re);
            wsh.im = shr1(wsh.im);
        }
    }
    if (widu == 0) {
        C2 x = x0;
        for (int j = 0; j < 64; ++j) {
            Abuf[j*64 + ((lane + j) & 63)] = st2(x);
            const float sjr = rdl(so.re, j);
            const float sji = rdl(so.im, j);
            const float nr = g.re*x.re - g.im*x.im + sjr*q.re - sji*q.im;
            const float ni = g.re*x.im + g.im*x.re + sjr*q.im + sji*q.re;
            x.re = nr; x.im = ni;
        }
    } else if (widu == 1) {
        C2 pp = rdl2(so, 0);
        C2 dd = {0,0};
        for (int i = 1; i <= 62; ++i) {
            const C2 ti = rdl2(so, i);
            const C2 nd = cadd(cmul(dd, g), pp);
            pp = cadd(cmul(pp, g), ti);
            dd = nd;
        }
        TgA[lane] = st2(cmul(g, pp));
        TpA[lane] = st2(cadd(pp, cmul(g, dd)));
    }
    __syncthreads();

    C2 Mk[8];
    {
        const C2 Tgm = ld2(TgA[lane]);
        #pragma unroll
        for (int k = 0; k < 8; ++k) {
            const int n = 8*widu + k;
            const C2 gn   = rdl2(g,   n);
            const C2 qn   = rdl2(q,   n);
            const C2 g64n = rdl2(g64, n);
            const C2 Tgn  = rdl2(Tgm, n);
            const C2 idm  = cinv(csub(gn, g));
            const C2 num  = cmul(r, cadd(csub(g64n, g64), csub(Tgn, Tgm)));
            Mk[k] = cmul(cmul(qn, num), idm);
        }
        if ((lane >> 3) == widu) {
            const int k0 = lane & 7;
            const C2 Tp  = ld2(TpA[lane]);
            const C2 g63 = cmul(g64, cinv(g));
            const C2 Sd  = cmul(r, cadd(cscale(64.0f, g63), Tp));
            Mk[k0] = cadd(g64, cmul(q, Sd));
        }
    }

    C2 Ci = Cv;
    for (int i = 0; i < 32; ++i) {
        if (widu == 0) Cs[i*64 + lane] = st2(Ci);
        if (i == 31) break;
        C2 acc = {0,0};
        #pragma unroll
        for (int k = 0; k < 8; ++k) {
            const float cr  = rdl(Ci.re, 8*widu + k);
            const float cim = rdl(Ci.im, 8*widu + k);
            acc.re += cr*Mk[k].re - cim*Mk[k].im;
            acc.im += cr*Mk[k].im + cim*Mk[k].re;
        }
        float2* buf = prt + (i & 1)*512;
        buf[widu*64 + lane] = st2(acc);
        __syncthreads();
        C2 nc = {0,0};
        for (int w2 = 0; w2 < 8; ++w2) {
            const float2 pv = buf[w2*64 + lane];
            nc.re += pv.x; nc.im += pv.y;
        }
        Ci = nc;
    }
    __syncthreads();

    {
        const int j = lane;
        C2 Csr[4];
        #pragma unroll
        for (int rr = 0; rr < 4; ++rr) Csr[rr] = ld2(Cs[(4*widu + rr)*64 + lane]);
        float accK[4] = {0,0,0,0};
        #pragma unroll 8
        for (int n = 0; n < 64; ++n) {
            const float2 xv = Abuf[j*64 + ((n + j) & 63)];
            #pragma unroll
            for (int rr = 0; rr < 4; ++rr)
                accK[rr] += rdl(Csr[rr].re, n)*xv.x - rdl(Csr[rr].im, n)*xv.y;
        }
        float* outh = out + h * LL;
        #pragma unroll
        for (int rr = 0; rr < 4; ++rr)
            outh[(4*widu + rr)*64 + j] = 2.0f * accK[rr];
    }
}

extern "C" void kernel_launch(void* const* d_in, const int* in_sizes, int n_in,
                              void* d_out, int out_size, void* d_ws, size_t ws_size,
                              hipStream_t stream) {
    const float* A_real = (const float*)d_in[0];
    const float* A_imag = (const float*)d_in[1];
    const float* B_real = (const float*)d_in[2];
    const float* B_imag = (const float*)d_in[3];
    const float* P_real = (const float*)d_in[4];
    const float* P_imag = (const float*)d_in[5];
    const float* C_real = (const float*)d_in[6];
    const float* C_imag = (const float*)d_in[7];
    const float* log_dt = (const float*)d_in[8];
    float* out = (float*)d_out;

    const size_t ws_needed = (size_t)256 * 6144 * sizeof(float2);  // 12.6 MB
    if (ws_size >= ws_needed) {
        ssm_k1<<<256, 256, 54272, stream>>>(
            A_real, A_imag, B_real, B_imag, P_real, P_imag,
            C_real, C_imag, log_dt, (float2*)d_ws);
        ssm_k2<<<1024, 256, 36864, stream>>>((const float2*)d_ws, out);
    } else {
        ssm_dplr_kernel<<<256, 512, 58368, stream>>>(
            A_real, A_imag, B_real, B_imag, P_real, P_imag,
            C_real, C_imag, log_dt, out);
    }
}